// Round 1
// 65.859 us; speedup vs baseline: 1.0030x; 1.0030x over previous
//
#include <hip/hip_runtime.h>

#define BB 4
#define CC 64
#define C2 32            // channel pairs
#define HH 64
#define WW 64
#define PATCH 9
#define HALF 4
#define P2 81
#define HW 4096
#define IMG (CC * HW)

typedef _Float16 v2h __attribute__((ext_vector_type(2)));

static __device__ __forceinline__ unsigned pk(float a, float b) {
    v2h h = {(_Float16)a, (_Float16)b};
    return __builtin_bit_cast(unsigned, h);
}
static __device__ __forceinline__ v2h bch(unsigned u) {
    return __builtin_bit_cast(v2h, u);
}

// One SINGLE-WAVE block per (b, y, dy): 2304 blocks x 64 threads.
// XCD-aware decode (xcd = bid & 7) keeps each XCD's f1/f2 working set in its L2.
//
// v2 change: 2 output columns per lane. Lane (m = tid&31, h = tid>>5) owns
// x0 = 2m, x1 = 2m+1 for channel half h (c2 = 16h..16h+15). The 10-col tap
// window (padded cols 2m..2m+9) is read as 5 aligned ds_read_b64 and shared
// by both x's -> LDS bytes/instr in the tap loop drop ~2x (was 9 b32 per c2
// per single x). f1 loads drop 64 scalar dwords -> 32 float2. Channel halves
// are summed with __shfl_xor(...,32); epilogue stores by parity (x = 2m+h).
__global__ __launch_bounds__(64) void corr_kernel(const float* __restrict__ f1,
                                                  const float* __restrict__ f2,
                                                  float* __restrict__ out) {
    __shared__ unsigned sB[C2 * 72];   // [c2][72 cols]; cols 0..3,68..71 zero (9.2 KB)
    __shared__ float sS2[64];          // f2 column inverse norms (real cols)

    const int tid = threadIdx.x;       // 0..63
    const int m   = tid & 31;          // column pair index: x0=2m, x1=2m+1
    const int h   = tid >> 5;          // channel half
    const int bid = blockIdx.x;
    // swizzled decode: xcd = bid & 7 -> y octave; slot enumerates (b, yo, dy)
    const int xcd = bid & 7;
    const int s   = bid >> 3;          // 0..287
    const int b   = s / 72;
    const int r   = s - b * 72;        // 0..71
    const int yo  = r / 9;
    const int dy  = r - yo * 9;
    const int y   = xcd * 8 + yo;
    const int y2  = y + dy - HALF;

    const int xx = 2 * m + h;          // lane's store column (parity split)
    float* ob = out + b * (P2 * HW) + y * WW + xx;

    if ((unsigned)y2 >= HH) {          // whole dy-row out of bounds -> zeros
#pragma unroll
        for (int dx = 0; dx < PATCH; ++dx)
            ob[(dy * PATCH + dx) * HW] = 0.f;
        return;
    }

    // ---- f1 cols x0,x1 for this lane's 32 channels: float2 loads + pack ----
    const float* f1r = f1 + b * IMG + y * WW + 2 * m;
    unsigned a0[16], a1[16];
    float ssq1_0 = 0.f, ssq1_1 = 0.f;
#pragma unroll
    for (int i = 0; i < 16; ++i) {
        const int c = 32 * h + 2 * i;  // channel pair base for this half
        float2 va = *(const float2*)(f1r + c * HW);
        float2 vb = *(const float2*)(f1r + (c + 1) * HW);
        ssq1_0 = fmaf(va.x, va.x, fmaf(vb.x, vb.x, ssq1_0));
        ssq1_1 = fmaf(va.y, va.y, fmaf(vb.y, vb.y, ssq1_1));
        a0[i] = pk(va.x, vb.x);
        a1[i] = pk(va.y, vb.y);
    }

    // ---- stage f2 row y2 into LDS packed [c2][72], zero pads (unchanged) ----
    const float* f2r = f2 + b * IMG + y2 * WW;
#pragma unroll
    for (int it = 0; it < 8; ++it) {
        int item = tid + it * 64;      // 512 items: (c2, k)
        int c2 = item >> 4, k = item & 15;
        const float* p = f2r + 4 * k;
        float4 va = *(const float4*)(p + (2 * c2) * HW);
        float4 vb = *(const float4*)(p + (2 * c2 + 1) * HW);
        uint4 u = {pk(va.x, vb.x), pk(va.y, vb.y), pk(va.z, vb.z), pk(va.w, vb.w)};
        *(uint4*)&sB[c2 * 72 + 4 + 4 * k] = u;
    }
#pragma unroll
    for (int it = 0; it < 4; ++it) {   // 256 pad dwords: cols 0..3 and 68..71
        int j = tid + it * 64;
        int c2 = j >> 3, e = j & 7;
        sB[c2 * 72 + (e < 4 ? e : 64 + e)] = 0u;
    }
    __syncthreads();                   // single wave: just a waitcnt

    // ---- main loop: 16 c2 x (5 aligned b64 window reads + 18+2 fdot2) ----
    float acc0[PATCH], acc1[PATCH];
#pragma unroll
    for (int i = 0; i < PATCH; ++i) { acc0[i] = 0.f; acc1[i] = 0.f; }
    float ssq2_0 = 0.f, ssq2_1 = 0.f;
#pragma unroll
    for (int i = 0; i < 16; ++i) {
        const unsigned* br = &sB[(16 * h + i) * 72 + 2 * m];  // padded col 2m
        uint2 p0 = *(const uint2*)(br + 0);   // cols 2m..2m+1   (8B aligned)
        uint2 p1 = *(const uint2*)(br + 2);
        uint2 p2 = *(const uint2*)(br + 4);
        uint2 p3 = *(const uint2*)(br + 6);
        uint2 p4 = *(const uint2*)(br + 8);   // cols 2m+8..2m+9
        v2h w[10] = {bch(p0.x), bch(p0.y), bch(p1.x), bch(p1.y), bch(p2.x),
                     bch(p2.y), bch(p3.x), bch(p3.y), bch(p4.x), bch(p4.y)};
        v2h A0 = bch(a0[i]), A1 = bch(a1[i]);
#pragma unroll
        for (int dx = 0; dx < PATCH; ++dx) {
            acc0[dx] = __builtin_amdgcn_fdot2(A0, w[dx],     acc0[dx], false);
            acc1[dx] = __builtin_amdgcn_fdot2(A1, w[dx + 1], acc1[dx], false);
        }
        // padded col 2m+4 == real col 2m; 2m+5 == real col 2m+1
        ssq2_0 = __builtin_amdgcn_fdot2(w[4], w[4], ssq2_0, false);
        ssq2_1 = __builtin_amdgcn_fdot2(w[5], w[5], ssq2_1, false);
    }

    // ---- cross-half reduction (lane ^ 32): 18 accs + 4 sumsq ----
#pragma unroll
    for (int dx = 0; dx < PATCH; ++dx) {
        acc0[dx] += __shfl_xor(acc0[dx], 32);
        acc1[dx] += __shfl_xor(acc1[dx], 32);
    }
    ssq1_0 += __shfl_xor(ssq1_0, 32);
    ssq1_1 += __shfl_xor(ssq1_1, 32);
    ssq2_0 += __shfl_xor(ssq2_0, 32);
    ssq2_1 += __shfl_xor(ssq2_1, 32);

    sS2[xx] = rsqrtf((h ? ssq2_1 : ssq2_0) + 1e-6f);
    __syncthreads();                   // intra-wave LDS visibility

    const float s1 = rsqrtf((h ? ssq1_1 : ssq1_0) + 1e-6f);
#pragma unroll
    for (int dx = 0; dx < PATCH; ++dx) {
        float av = h ? acc1[dx] : acc0[dx];  // parity-select this lane's x
        int col = xx + dx - HALF;
        col = min(max(col, 0), WW - 1);      // OOB taps have acc==0
        ob[(dy * PATCH + dx) * HW] = fmaxf(av * s1 * sS2[col], 0.f);
    }
}

extern "C" void kernel_launch(void* const* d_in, const int* in_sizes, int n_in,
                              void* d_out, int out_size, void* d_ws, size_t ws_size,
                              hipStream_t stream) {
    const float* f1 = (const float*)d_in[0];
    const float* f2 = (const float*)d_in[1];
    float* out = (float*)d_out;
    (void)d_ws; (void)ws_size;

    corr_kernel<<<BB * HH * PATCH, 64, 0, stream>>>(f1, f2, out);
}